// Round 14
// baseline (750.946 us; speedup 1.0000x reference)
//
#include <hip/hip_runtime.h>
#include <stdint.h>

#define B_DIM 8
#define T_DIM 4096
#define K_DIM 1024
#define H_DIM 1024
#define M_DIM (B_DIM * T_DIM)      // 32768
#define CHUNK 64
#define NCHUNK (T_DIM / CHUNK)     // 64

typedef __attribute__((ext_vector_type(8))) short s16x8;
typedef __attribute__((ext_vector_type(4))) float f32x4;

__device__ __forceinline__ unsigned short f2b(float f) {
    union { float f; uint32_t u; } c; c.f = f;
    uint32_t r = (c.u + 0x7fffu + ((c.u >> 16) & 1u)) >> 16;
    return (unsigned short)r;
}
__device__ __forceinline__ float b2f(unsigned short u) {
    union { uint32_t u; float f; } c; c.u = ((uint32_t)u) << 16;
    return c.f;
}

// async global->LDS, 16B per lane. LDS dest = wave-uniform base + lane*16.
__device__ __forceinline__ void gload_lds16(const unsigned short* g,
                                            unsigned short* l) {
    __builtin_amdgcn_global_load_lds(
        (__attribute__((address_space(1))) void*)g,
        (__attribute__((address_space(3))) void*)l, 16, 0, 0);
}

__device__ __forceinline__ void bar() {
    asm volatile("s_barrier" ::: "memory");
}

// ---------------- merged conversion kernel ----------------

__device__ __forceinline__ ushort4 cvu4(float4 v) {
    ushort4 o;
    o.x = f2b(v.x); o.y = f2b(v.y); o.z = f2b(v.z); o.w = f2b(v.w);
    return o;
}

// x -> xb; W_hg -> interleaved Wp (row 2c=hidden c, 2c+1=gate c); W_out -> Wob
__global__ void cvt_all(const float* __restrict__ x,
                        const float* __restrict__ Whg,
                        const float* __restrict__ Wout,
                        unsigned short* __restrict__ xb,
                        unsigned short* __restrict__ Wp,
                        unsigned short* __restrict__ Wob) {
    const int NX = M_DIM * K_DIM / 4;
    const int NW = 2 * H_DIM * K_DIM / 4;
    const int NO = H_DIM * K_DIM / 4;
    int stride = gridDim.x * blockDim.x;
    for (int i = blockIdx.x * blockDim.x + threadIdx.x; i < NX + NW + NO;
         i += stride) {
        if (i < NX) {
            ((ushort4*)xb)[i] = cvu4(((const float4*)x)[i]);
        } else if (i < NX + NW) {
            int j = i - NX;
            int e = j * 4;
            int n = e >> 10;          // K = 1024
            int k = e & 1023;
            int src = (n & 1) ? (H_DIM + (n >> 1)) : (n >> 1);
            *(ushort4*)&Wp[(size_t)n * K_DIM + k] =
                cvu4(*(const float4*)&Whg[(size_t)src * K_DIM + k]);
        } else {
            int j = i - NX - NW;
            ((ushort4*)Wob)[j] = cvu4(((const float4*)Wout)[j]);
        }
    }
}

// ---------------- GEMM1: 256x256 4-phase bf16 MFMA (R4 schedule, frozen) ----
// Staging spread 3/3/2 over phases 1-3; validation vmcnt(0) in phase 4.
// dbuf LDS 128KB, XOR slot-swizzle via pre-swizzled global source.
// Fused minGRU gating epilogue -> packed u32 Sab[row][ch] =
//         {lo: bf16(1-g), hi: bf16(g*hidden)}.

__global__ __launch_bounds__(512, 2) void gemm1(
    const unsigned short* __restrict__ A,
    const unsigned short* __restrict__ Bm,
    uint32_t* __restrict__ Sab,
    int N) {
    __shared__ unsigned short As[2][256 * 64];
    __shared__ unsigned short Bs[2][256 * 64];
    const int K = K_DIM;
    const int KT = K / 64;

    const int gx = gridDim.x;
    const int nwg = gx * gridDim.y;
    const int orig = blockIdx.y * gx + blockIdx.x;
    const int cpx = nwg >> 3;
    const int wg = (orig & 7) * cpx + (orig >> 3);
    const int m0 = (wg / gx) * 256;
    const int n0 = (wg % gx) * 256;

    const int t = threadIdx.x;
    const int lane = t & 63;
    const int w = t >> 6;               // 0..7
    const int wm = w >> 2, wn = w & 3;  // 2 x 4 wave grid

    const int lrow = lane >> 3;
    const int lslot = (lane & 7) ^ lrow;

    const int l15 = lane & 15;
    const int rq = lane >> 4;          // 0..3
    const int rx = l15 & 7;

    f32x4 acc[8][4];
#pragma unroll
    for (int m = 0; m < 8; m++)
#pragma unroll
        for (int n = 0; n < 4; n++) acc[m][n] = (f32x4){0.f, 0.f, 0.f, 0.f};

    auto stageA = [&](int kt, int buf, int j) {
        const int seg = j * 8 + w;
        const int row = seg * 8 + lrow;
        gload_lds16(&A[(size_t)(m0 + row) * K + kt * 64 + lslot * 8],
                    &As[buf][seg * 512]);
    };
    auto stageB = [&](int kt, int buf, int j) {
        const int seg = j * 8 + w;
        const int row = seg * 8 + lrow;
        gload_lds16(&Bm[(size_t)(n0 + row) * K + kt * 64 + lslot * 8],
                    &Bs[buf][seg * 512]);
    };

    s16x8 af[4], bf[4];

#define LDA(buf, mi, ks) \
    (*(const s16x8*)&As[buf][(wm * 128 + (mi) * 16 + l15) * 64 + (((rq + (ks) * 4) ^ rx) * 8)])
#define LDB(buf, ni, ks) \
    (*(const s16x8*)&Bs[buf][(wn * 64 + (ni) * 16 + l15) * 64 + (((rq + (ks) * 4) ^ rx) * 8)])

#define MFMA16(MB)                                                          \
    __builtin_amdgcn_s_setprio(1);                                          \
    _Pragma("unroll") for (int m = 0; m < 4; m++)                           \
        _Pragma("unroll") for (int n = 0; n < 4; n++)                       \
            acc[MB + m][n] = __builtin_amdgcn_mfma_f32_16x16x32_bf16(       \
                af[m], bf[n], acc[MB + m][n], 0, 0, 0);                     \
    __builtin_amdgcn_s_setprio(0);

    {
#pragma unroll
        for (int j = 0; j < 4; j++) stageA(0, 0, j);
#pragma unroll
        for (int j = 0; j < 4; j++) stageB(0, 0, j);
        asm volatile("s_waitcnt vmcnt(0)" ::: "memory");
        bar();
    }

    for (int kt = 0; kt < KT; ++kt) {
        const int buf = kt & 1;
        const int nb = buf ^ 1;
        const bool nx = (kt + 1 < KT);
        // ---- phase 1
#pragma unroll
        for (int m = 0; m < 4; m++) af[m] = LDA(buf, m, 0);
#pragma unroll
        for (int n = 0; n < 4; n++) bf[n] = LDB(buf, n, 0);
        if (nx) { stageA(kt + 1, nb, 0); stageA(kt + 1, nb, 1); stageB(kt + 1, nb, 0); }
        bar();
        MFMA16(0);
        bar();
        // ---- phase 2
#pragma unroll
        for (int m = 0; m < 4; m++) af[m] = LDA(buf, m + 4, 0);
        if (nx) { stageA(kt + 1, nb, 2); stageA(kt + 1, nb, 3); stageB(kt + 1, nb, 1); }
        bar();
        MFMA16(4);
        bar();
        // ---- phase 3
#pragma unroll
        for (int m = 0; m < 4; m++) af[m] = LDA(buf, m, 1);
#pragma unroll
        for (int n = 0; n < 4; n++) bf[n] = LDB(buf, n, 1);
        if (nx) { stageB(kt + 1, nb, 2); stageB(kt + 1, nb, 3); }
        bar();
        MFMA16(0);
        bar();
        // ---- phase 4: pipelined validation of tile kt+1
#pragma unroll
        for (int m = 0; m < 4; m++) af[m] = LDA(buf, m + 4, 1);
        asm volatile("s_waitcnt vmcnt(0)" ::: "memory");
        bar();
        MFMA16(4);
        bar();
    }

    // ---- epilogue: gating + pack
    const int lr4 = rq * 4;
#pragma unroll
    for (int m = 0; m < 8; m++) {
#pragma unroll
        for (int n = 0; n < 4; n++) {
#pragma unroll
            for (int r = 0; r < 4; r++) {
                const int row = m0 + wm * 128 + m * 16 + lr4 + r;
                const int col = n0 + wn * 64 + n * 16 + l15;
                float v = acc[m][n][r];
                float o = __shfl_xor(v, 1);   // all lanes execute
                if ((lane & 1) == 0) {
                    float g = 1.f / (1.f + __expf(-o));
                    uint32_t pk = (uint32_t)f2b(1.f - g) |
                                  ((uint32_t)f2b(g * v) << 16);
                    Sab[(size_t)row * H_DIM + (col >> 1)] = pk;
                }
            }
        }
    }
#undef LDA
#undef LDB
#undef MFMA16
}

// ---------------- GEMM2: 256x256, BK=32, 64KB LDS -> 2 blocks/CU -----------
// Same 1KB-unit LDS layout (16 units of 16rows x 32k per tile, HW-linear
// staging, contiguous wave reads). R4-style: stage spread 3/1 over 2 phases,
// single vmcnt(0) at phase 2 end; cross-block wave overlap (2 blocks/CU,
// m97/m114 mechanism) hides the drain. C = f32 out.

__global__ __launch_bounds__(512, 4) void gemm2(
    const unsigned short* __restrict__ A,
    const unsigned short* __restrict__ Bm,
    float* __restrict__ C,
    int N) {
    __shared__ unsigned short As[2][256 * 32];
    __shared__ unsigned short Bs[2][256 * 32];
    const int K = K_DIM;
    const int KT = K / 32;   // 32

    const int gx = gridDim.x;
    const int nwg = gx * gridDim.y;
    const int orig = blockIdx.y * gx + blockIdx.x;
    const int cpx = nwg >> 3;
    const int wg = (orig & 7) * cpx + (orig >> 3);
    const int m0 = (wg / gx) * 256;
    const int n0 = (wg % gx) * 256;

    const int t = threadIdx.x;
    const int lane = t & 63;
    const int w = t >> 6;               // 0..7
    const int wm = w >> 2, wn = w & 3;  // 2 x 4 wave grid

    // staging lane geometry (1KB unit = 16 rows x 32 k): row lane&15, kq lane>>4
    const int srow = lane & 15;
    const int sq   = lane >> 4;

    const int l15 = lane & 15;
    const int rq  = lane >> 4;

    f32x4 acc[8][4];
#pragma unroll
    for (int m = 0; m < 8; m++)
#pragma unroll
        for (int n = 0; n < 4; n++) acc[m][n] = (f32x4){0.f, 0.f, 0.f, 0.f};

    // stage unit u = j*8+w (16 rows) of tile kt into buf
    auto stA = [&](int kt, int buf, int j) {
        const int u = j * 8 + w;
        gload_lds16(&A[(size_t)(m0 + u * 16 + srow) * K + kt * 32 + sq * 8],
                    &As[buf][u * 512]);
    };
    auto stB = [&](int kt, int buf, int j) {
        const int u = j * 8 + w;
        gload_lds16(&Bm[(size_t)(n0 + u * 16 + srow) * K + kt * 32 + sq * 8],
                    &Bs[buf][u * 512]);
    };

    s16x8 af[4], bf[4];

    // reads: unit (rowblk)*512 + rq*128 + l15*8 (contiguous 1KB per wave)
#define LDAX(buf, mi) \
    (*(const s16x8*)&As[buf][(wm * 8 + (mi)) * 512 + rq * 128 + l15 * 8])
#define LDBX(buf, ni) \
    (*(const s16x8*)&Bs[buf][(wn * 4 + (ni)) * 512 + rq * 128 + l15 * 8])

#define MFMA16(MB)                                                          \
    __builtin_amdgcn_s_setprio(1);                                          \
    _Pragma("unroll") for (int m = 0; m < 4; m++)                           \
        _Pragma("unroll") for (int n = 0; n < 4; n++)                       \
            acc[MB + m][n] = __builtin_amdgcn_mfma_f32_16x16x32_bf16(       \
                af[m], bf[n], acc[MB + m][n], 0, 0, 0);                     \
    __builtin_amdgcn_s_setprio(0);

    // prologue: stage tile 0 (A: j0,j1; B: j0,j1), validate
    {
        stA(0, 0, 0); stA(0, 0, 1); stB(0, 0, 0); stB(0, 0, 1);
        asm volatile("s_waitcnt vmcnt(0)" ::: "memory");
        bar();
    }

    for (int kt = 0; kt < KT; ++kt) {
        const int buf = kt & 1;
        const int nb = buf ^ 1;
        const bool nx = (kt + 1 < KT);
        // ---- phase 1: reads m0-3 + B; stage 3 of tile kt+1
#pragma unroll
        for (int m = 0; m < 4; m++) af[m] = LDAX(buf, m);
#pragma unroll
        for (int n = 0; n < 4; n++) bf[n] = LDBX(buf, n);
        if (nx) { stA(kt + 1, nb, 0); stA(kt + 1, nb, 1); stB(kt + 1, nb, 0); }
        bar();
        MFMA16(0);
        bar();
        // ---- phase 2: reads m4-7; stage 1; validate tile kt+1
#pragma unroll
        for (int m = 0; m < 4; m++) af[m] = LDAX(buf, m + 4);
        if (nx) { stB(kt + 1, nb, 1); }
        asm volatile("s_waitcnt vmcnt(0)" ::: "memory");
        bar();
        MFMA16(4);
        bar();
    }

    // ---- epilogue: f32 store
    const int lr4 = rq * 4;
#pragma unroll
    for (int m = 0; m < 8; m++)
#pragma unroll
        for (int n = 0; n < 4; n++)
#pragma unroll
            for (int r = 0; r < 4; r++) {
                const int row = m0 + wm * 128 + m * 16 + lr4 + r;
                const int col = n0 + wn * 64 + n * 16 + l15;
                C[(size_t)row * N + col] = acc[m][n][r];
            }
#undef LDAX
#undef LDBX
#undef MFMA16
}

// ---------------- chunked scan (3-pass, packed coefficients) ----------------
// Element combine (matches reference): carry (A,Bv); element (a,b,r):
//   r>0 : (A,Bv) = (a, b)      else : (A,Bv) = (a*A, a*Bv + b)

__global__ __launch_bounds__(256) void scan_chunks(
    const uint32_t* __restrict__ Sab, const float* __restrict__ is_init,
    float* __restrict__ CA, float* __restrict__ CB, float* __restrict__ CR) {
    int idx = blockIdx.x * 256 + threadIdx.x;      // b*65536 + chunk*1024 + ch
    int ch = idx & (H_DIM - 1);
    int chunk = (idx >> 10) & (NCHUNK - 1);
    int b = idx >> 16;
    int t0 = chunk * CHUNK;
    size_t base = ((size_t)b * T_DIM + t0) * H_DIM + ch;
    const float* ii = is_init + (size_t)b * T_DIM + t0;
    float A = 1.f, Bv = 0.f;
    int rf = 0;
    for (int i = 0; i < CHUNK; i++) {
        uint32_t d = Sab[base + (size_t)i * H_DIM];
        float a = b2f((unsigned short)(d & 0xffffu));
        float bb = b2f((unsigned short)(d >> 16));
        bool rst = ii[i] > 0.f;
        A = rst ? a : a * A;
        Bv = rst ? bb : fmaf(a, Bv, bb);
        rf |= (int)rst;
    }
    size_t o = ((size_t)b * NCHUNK + chunk) * H_DIM + ch;
    CA[o] = A;
    CB[o] = Bv;
    if (ch == 0) CR[b * NCHUNK + chunk] = (float)rf;
}

__global__ void scan_tops(const float* __restrict__ CA, const float* __restrict__ CB,
                          const float* __restrict__ CR,
                          float* __restrict__ PA, float* __restrict__ PB) {
    int idx = blockIdx.x * blockDim.x + threadIdx.x;   // 0 .. B*H-1
    if (idx >= B_DIM * H_DIM) return;
    int ch = idx & (H_DIM - 1);
    int b = idx >> 10;
    float A = 1.f, Bv = 0.f;
    for (int c = 0; c < NCHUNK; c++) {
        size_t o = ((size_t)b * NCHUNK + c) * H_DIM + ch;
        PA[o] = A;            // exclusive prefix
        PB[o] = Bv;
        float a = CA[o], bb = CB[o];
        bool rst = CR[b * NCHUNK + c] > 0.f;
        float nA = rst ? a : a * A;
        float nB = rst ? bb : fmaf(a, Bv, bb);
        A = nA; Bv = nB;
    }
}

__global__ __launch_bounds__(256) void scan_apply(
    const uint32_t* __restrict__ Sab, const float* __restrict__ is_init,
    const float* __restrict__ PA, const float* __restrict__ PB,
    const float* __restrict__ h0,
    unsigned short* __restrict__ hb, float* __restrict__ hn) {
    int idx = blockIdx.x * 256 + threadIdx.x;
    int ch = idx & (H_DIM - 1);
    int chunk = (idx >> 10) & (NCHUNK - 1);
    int b = idx >> 16;
    int t0 = chunk * CHUNK;
    size_t base = ((size_t)b * T_DIM + t0) * H_DIM + ch;
    const float* ii = is_init + (size_t)b * T_DIM + t0;
    size_t po = ((size_t)b * NCHUNK + chunk) * H_DIM + ch;
    float A = PA[po], Bv = PB[po];
    float h0v = h0[b * H_DIM + ch];
    float h = 0.f;
    for (int i = 0; i < CHUNK; i++) {
        uint32_t d = Sab[base + (size_t)i * H_DIM];
        float a = b2f((unsigned short)(d & 0xffffu));
        float bb = b2f((unsigned short)(d >> 16));
        bool rst = ii[i] > 0.f;
        A = rst ? a : a * A;
        Bv = rst ? bb : fmaf(a, Bv, bb);
        h = fmaf(A, h0v, Bv);
        hb[base + (size_t)i * H_DIM] = f2b(h);
    }
    if (chunk == NCHUNK - 1) hn[b * H_DIM + ch] = h;
}

// ---------------- launcher ----------------

extern "C" void kernel_launch(void* const* d_in, const int* in_sizes, int n_in,
                              void* d_out, int out_size, void* d_ws, size_t ws_size,
                              hipStream_t stream) {
    const float* x       = (const float*)d_in[0];
    const float* W_hg    = (const float*)d_in[1];
    const float* W_out   = (const float*)d_in[2];
    const float* is_init = (const float*)d_in[3];
    const float* h0      = (const float*)d_in[4];
    float* out = (float*)d_out;
    float* hn  = out + (size_t)M_DIM * H_DIM;

    char* ws = (char*)d_ws;
    size_t off = 0;
    auto alloc = [&](size_t bytes) {
        void* p = ws + off;
        off += (bytes + 255) & ~(size_t)255;
        return p;
    };
    unsigned short* xb  = (unsigned short*)alloc((size_t)M_DIM * K_DIM * 2); // reused as hb
    unsigned short* Wp  = (unsigned short*)alloc((size_t)2 * H_DIM * K_DIM * 2);
    unsigned short* Wob = (unsigned short*)alloc((size_t)H_DIM * K_DIM * 2);
    uint32_t* Sab = (uint32_t*)alloc((size_t)M_DIM * H_DIM * 4);
    float* CA = (float*)alloc((size_t)B_DIM * NCHUNK * H_DIM * 4);
    float* CB = (float*)alloc((size_t)B_DIM * NCHUNK * H_DIM * 4);
    float* CR = (float*)alloc((size_t)B_DIM * NCHUNK * 4);
    float* PA = (float*)alloc((size_t)B_DIM * NCHUNK * H_DIM * 4);
    float* PB = (float*)alloc((size_t)B_DIM * NCHUNK * H_DIM * 4);
    unsigned short* hb = xb;   // alias: x_bf16 dead after GEMM1

    // 1) conversions (single launch)
    cvt_all<<<2048, 256, 0, stream>>>(x, W_hg, W_out, xb, Wp, Wob);

    // 2) GEMM1 with fused gating epilogue (N = 2048 interleaved cols)
    gemm1<<<dim3(2048 / 256, M_DIM / 256), 512, 0, stream>>>(
        xb, Wp, Sab, 2048);

    // 3) 3-pass chunked scan over time (packed coefficients)
    scan_chunks<<<(B_DIM * NCHUNK * H_DIM) / 256, 256, 0, stream>>>(
        Sab, is_init, CA, CB, CR);
    scan_tops<<<(B_DIM * H_DIM + 255) / 256, 256, 0, stream>>>(CA, CB, CR, PA, PB);
    scan_apply<<<(B_DIM * NCHUNK * H_DIM) / 256, 256, 0, stream>>>(
        Sab, is_init, PA, PB, h0, hb, hn);

    // 4) GEMM2: out = h @ W_out^T  (BK=32, 2 blocks/CU)
    gemm2<<<dim3(1024 / 256, M_DIM / 256), 512, 0, stream>>>(
        hb, Wob, out, 1024);
}

// Round 15
// 676.923 us; speedup vs baseline: 1.1094x; 1.1094x over previous
//
#include <hip/hip_runtime.h>
#include <stdint.h>

#define B_DIM 8
#define T_DIM 4096
#define K_DIM 1024
#define H_DIM 1024
#define M_DIM (B_DIM * T_DIM)      // 32768
#define CHUNK 64
#define NCHUNK (T_DIM / CHUNK)     // 64

typedef __attribute__((ext_vector_type(8))) short s16x8;
typedef __attribute__((ext_vector_type(4))) float f32x4;

__device__ __forceinline__ unsigned short f2b(float f) {
    union { float f; uint32_t u; } c; c.f = f;
    uint32_t r = (c.u + 0x7fffu + ((c.u >> 16) & 1u)) >> 16;
    return (unsigned short)r;
}
__device__ __forceinline__ float b2f(unsigned short u) {
    union { uint32_t u; float f; } c; c.u = ((uint32_t)u) << 16;
    return c.f;
}

// async global->LDS, 16B per lane. LDS dest = wave-uniform base + lane*16.
__device__ __forceinline__ void gload_lds16(const unsigned short* g,
                                            unsigned short* l) {
    __builtin_amdgcn_global_load_lds(
        (__attribute__((address_space(1))) void*)g,
        (__attribute__((address_space(3))) void*)l, 16, 0, 0);
}

__device__ __forceinline__ void bar() {
    asm volatile("s_barrier" ::: "memory");
}

// ---------------- merged conversion kernel ----------------

__device__ __forceinline__ ushort4 cvu4(float4 v) {
    ushort4 o;
    o.x = f2b(v.x); o.y = f2b(v.y); o.z = f2b(v.z); o.w = f2b(v.w);
    return o;
}

// x -> xb; W_hg -> interleaved Wp (row 2c=hidden c, 2c+1=gate c); W_out -> Wob
__global__ void cvt_all(const float* __restrict__ x,
                        const float* __restrict__ Whg,
                        const float* __restrict__ Wout,
                        unsigned short* __restrict__ xb,
                        unsigned short* __restrict__ Wp,
                        unsigned short* __restrict__ Wob) {
    const int NX = M_DIM * K_DIM / 4;
    const int NW = 2 * H_DIM * K_DIM / 4;
    const int NO = H_DIM * K_DIM / 4;
    int stride = gridDim.x * blockDim.x;
    for (int i = blockIdx.x * blockDim.x + threadIdx.x; i < NX + NW + NO;
         i += stride) {
        if (i < NX) {
            ((ushort4*)xb)[i] = cvu4(((const float4*)x)[i]);
        } else if (i < NX + NW) {
            int j = i - NX;
            int e = j * 4;
            int n = e >> 10;          // K = 1024
            int k = e & 1023;
            int src = (n & 1) ? (H_DIM + (n >> 1)) : (n >> 1);
            *(ushort4*)&Wp[(size_t)n * K_DIM + k] =
                cvu4(*(const float4*)&Whg[(size_t)src * K_DIM + k]);
        } else {
            int j = i - NX - NW;
            ((ushort4*)Wob)[j] = cvu4(((const float4*)Wout)[j]);
        }
    }
}

// ---------------- GEMM1: 256x256 4-phase bf16 MFMA (R4 schedule, frozen) ----
// Staging spread 3/3/2 over phases 1-3; validation vmcnt(0) in phase 4.
// dbuf LDS 128KB, XOR slot-swizzle via pre-swizzled global source.
// Fused minGRU gating epilogue -> packed u32 Sab[row][ch] =
//         {lo: bf16(1-g), hi: bf16(g*hidden)}.

__global__ __launch_bounds__(512, 2) void gemm1(
    const unsigned short* __restrict__ A,
    const unsigned short* __restrict__ Bm,
    uint32_t* __restrict__ Sab,
    int N) {
    __shared__ unsigned short As[2][256 * 64];
    __shared__ unsigned short Bs[2][256 * 64];
    const int K = K_DIM;
    const int KT = K / 64;

    const int gx = gridDim.x;
    const int nwg = gx * gridDim.y;
    const int orig = blockIdx.y * gx + blockIdx.x;
    const int cpx = nwg >> 3;
    const int wg = (orig & 7) * cpx + (orig >> 3);
    const int m0 = (wg / gx) * 256;
    const int n0 = (wg % gx) * 256;

    const int t = threadIdx.x;
    const int lane = t & 63;
    const int w = t >> 6;               // 0..7
    const int wm = w >> 2, wn = w & 3;  // 2 x 4 wave grid

    const int lrow = lane >> 3;
    const int lslot = (lane & 7) ^ lrow;

    const int l15 = lane & 15;
    const int rq = lane >> 4;          // 0..3
    const int rx = l15 & 7;

    f32x4 acc[8][4];
#pragma unroll
    for (int m = 0; m < 8; m++)
#pragma unroll
        for (int n = 0; n < 4; n++) acc[m][n] = (f32x4){0.f, 0.f, 0.f, 0.f};

    auto stageA = [&](int kt, int buf, int j) {
        const int seg = j * 8 + w;
        const int row = seg * 8 + lrow;
        gload_lds16(&A[(size_t)(m0 + row) * K + kt * 64 + lslot * 8],
                    &As[buf][seg * 512]);
    };
    auto stageB = [&](int kt, int buf, int j) {
        const int seg = j * 8 + w;
        const int row = seg * 8 + lrow;
        gload_lds16(&Bm[(size_t)(n0 + row) * K + kt * 64 + lslot * 8],
                    &Bs[buf][seg * 512]);
    };

    s16x8 af[4], bf[4];

#define LDA(buf, mi, ks) \
    (*(const s16x8*)&As[buf][(wm * 128 + (mi) * 16 + l15) * 64 + (((rq + (ks) * 4) ^ rx) * 8)])
#define LDB(buf, ni, ks) \
    (*(const s16x8*)&Bs[buf][(wn * 64 + (ni) * 16 + l15) * 64 + (((rq + (ks) * 4) ^ rx) * 8)])

#define MFMA16(MB)                                                          \
    __builtin_amdgcn_s_setprio(1);                                          \
    _Pragma("unroll") for (int m = 0; m < 4; m++)                           \
        _Pragma("unroll") for (int n = 0; n < 4; n++)                       \
            acc[MB + m][n] = __builtin_amdgcn_mfma_f32_16x16x32_bf16(       \
                af[m], bf[n], acc[MB + m][n], 0, 0, 0);                     \
    __builtin_amdgcn_s_setprio(0);

    {
#pragma unroll
        for (int j = 0; j < 4; j++) stageA(0, 0, j);
#pragma unroll
        for (int j = 0; j < 4; j++) stageB(0, 0, j);
        asm volatile("s_waitcnt vmcnt(0)" ::: "memory");
        bar();
    }

    for (int kt = 0; kt < KT; ++kt) {
        const int buf = kt & 1;
        const int nb = buf ^ 1;
        const bool nx = (kt + 1 < KT);
        // ---- phase 1
#pragma unroll
        for (int m = 0; m < 4; m++) af[m] = LDA(buf, m, 0);
#pragma unroll
        for (int n = 0; n < 4; n++) bf[n] = LDB(buf, n, 0);
        if (nx) { stageA(kt + 1, nb, 0); stageA(kt + 1, nb, 1); stageB(kt + 1, nb, 0); }
        bar();
        MFMA16(0);
        bar();
        // ---- phase 2
#pragma unroll
        for (int m = 0; m < 4; m++) af[m] = LDA(buf, m + 4, 0);
        if (nx) { stageA(kt + 1, nb, 2); stageA(kt + 1, nb, 3); stageB(kt + 1, nb, 1); }
        bar();
        MFMA16(4);
        bar();
        // ---- phase 3
#pragma unroll
        for (int m = 0; m < 4; m++) af[m] = LDA(buf, m, 1);
#pragma unroll
        for (int n = 0; n < 4; n++) bf[n] = LDB(buf, n, 1);
        if (nx) { stageB(kt + 1, nb, 2); stageB(kt + 1, nb, 3); }
        bar();
        MFMA16(0);
        bar();
        // ---- phase 4: pipelined validation of tile kt+1
#pragma unroll
        for (int m = 0; m < 4; m++) af[m] = LDA(buf, m + 4, 1);
        asm volatile("s_waitcnt vmcnt(0)" ::: "memory");
        bar();
        MFMA16(4);
        bar();
    }

    // ---- epilogue: gating + pack
    const int lr4 = rq * 4;
#pragma unroll
    for (int m = 0; m < 8; m++) {
#pragma unroll
        for (int n = 0; n < 4; n++) {
#pragma unroll
            for (int r = 0; r < 4; r++) {
                const int row = m0 + wm * 128 + m * 16 + lr4 + r;
                const int col = n0 + wn * 64 + n * 16 + l15;
                float v = acc[m][n][r];
                float o = __shfl_xor(v, 1);   // all lanes execute
                if ((lane & 1) == 0) {
                    float g = 1.f / (1.f + __expf(-o));
                    uint32_t pk = (uint32_t)f2b(1.f - g) |
                                  ((uint32_t)f2b(g * v) << 16);
                    Sab[(size_t)row * H_DIM + (col >> 1)] = pk;
                }
            }
        }
    }
#undef LDA
#undef LDB
#undef MFMA16
}

// ---------------- GEMM2: 256x256, BK=64, single-buffered 64KB -> 2 blk/CU ---
// m97 2-barrier structure: stage 8 -> sync -> (24 ds_read + 64 MFMA,
// compiler-scheduled) -> sync. Per-tile vmcnt drain is hidden by the
// co-resident block's compute (m114 cross-block overlap). Full 128B row
// fetches (no R14 over-fetch). Same XOR-swizzled LDS geometry as GEMM1.

__global__ __launch_bounds__(512, 4) void gemm2(
    const unsigned short* __restrict__ A,
    const unsigned short* __restrict__ Bm,
    float* __restrict__ C,
    int N) {
    __shared__ unsigned short As[256 * 64];
    __shared__ unsigned short Bs[256 * 64];
    const int K = K_DIM;
    const int KT = K / 64;   // 16

    const int gx = gridDim.x;
    const int nwg = gx * gridDim.y;
    const int orig = blockIdx.y * gx + blockIdx.x;
    const int cpx = nwg >> 3;
    const int wg = (orig & 7) * cpx + (orig >> 3);
    const int m0 = (wg / gx) * 256;
    const int n0 = (wg % gx) * 256;

    const int t = threadIdx.x;
    const int lane = t & 63;
    const int w = t >> 6;               // 0..7
    const int wm = w >> 2, wn = w & 3;  // 2 x 4 wave grid

    const int lrow = lane >> 3;
    const int lslot = (lane & 7) ^ lrow;

    const int l15 = lane & 15;
    const int rq = lane >> 4;          // 0..3
    const int rx = l15 & 7;

    f32x4 acc[8][4];
#pragma unroll
    for (int m = 0; m < 8; m++)
#pragma unroll
        for (int n = 0; n < 4; n++) acc[m][n] = (f32x4){0.f, 0.f, 0.f, 0.f};

#define LDA2(mi, ks) \
    (*(const s16x8*)&As[(wm * 128 + (mi) * 16 + l15) * 64 + (((rq + (ks) * 4) ^ rx) * 8)])
#define LDB2(ni, ks) \
    (*(const s16x8*)&Bs[(wn * 64 + (ni) * 16 + l15) * 64 + (((rq + (ks) * 4) ^ rx) * 8)])

    for (int kt = 0; kt < KT; ++kt) {
        // ---- stage tile kt (8 gload_lds per thread-group; seg wave-uniform)
#pragma unroll
        for (int j = 0; j < 4; j++) {
            const int seg = j * 8 + w;
            const int row = seg * 8 + lrow;
            gload_lds16(&A[(size_t)(m0 + row) * K + kt * 64 + lslot * 8],
                        &As[seg * 512]);
            gload_lds16(&Bm[(size_t)(n0 + row) * K + kt * 64 + lslot * 8],
                        &Bs[seg * 512]);
        }
        __syncthreads();   // vmcnt drain; co-resident block computes meanwhile

        // ---- compute tile kt (compiler-scheduled)
#pragma unroll
        for (int ks = 0; ks < 2; ++ks) {
            s16x8 af[4], bf[4];
#pragma unroll
            for (int n = 0; n < 4; n++) bf[n] = LDB2(n, ks);
#pragma unroll
            for (int mh = 0; mh < 2; ++mh) {
#pragma unroll
                for (int m = 0; m < 4; m++) af[m] = LDA2(mh * 4 + m, ks);
#pragma unroll
                for (int m = 0; m < 4; m++)
#pragma unroll
                    for (int n = 0; n < 4; n++)
                        acc[mh * 4 + m][n] = __builtin_amdgcn_mfma_f32_16x16x32_bf16(
                            af[m], bf[n], acc[mh * 4 + m][n], 0, 0, 0);
            }
        }
        __syncthreads();   // reads done before next stage overwrites
    }

    // ---- epilogue: f32 store
    const int lr4 = rq * 4;
#pragma unroll
    for (int m = 0; m < 8; m++)
#pragma unroll
        for (int n = 0; n < 4; n++)
#pragma unroll
            for (int r = 0; r < 4; r++) {
                const int row = m0 + wm * 128 + m * 16 + lr4 + r;
                const int col = n0 + wn * 64 + n * 16 + l15;
                C[(size_t)row * N + col] = acc[m][n][r];
            }
#undef LDA2
#undef LDB2
}

// ---------------- chunked scan (3-pass, packed coefficients) ----------------
// Element combine (matches reference): carry (A,Bv); element (a,b,r):
//   r>0 : (A,Bv) = (a, b)      else : (A,Bv) = (a*A, a*Bv + b)

__global__ __launch_bounds__(256) void scan_chunks(
    const uint32_t* __restrict__ Sab, const float* __restrict__ is_init,
    float* __restrict__ CA, float* __restrict__ CB, float* __restrict__ CR) {
    int idx = blockIdx.x * 256 + threadIdx.x;      // b*65536 + chunk*1024 + ch
    int ch = idx & (H_DIM - 1);
    int chunk = (idx >> 10) & (NCHUNK - 1);
    int b = idx >> 16;
    int t0 = chunk * CHUNK;
    size_t base = ((size_t)b * T_DIM + t0) * H_DIM + ch;
    const float* ii = is_init + (size_t)b * T_DIM + t0;
    float A = 1.f, Bv = 0.f;
    int rf = 0;
    for (int i = 0; i < CHUNK; i++) {
        uint32_t d = Sab[base + (size_t)i * H_DIM];
        float a = b2f((unsigned short)(d & 0xffffu));
        float bb = b2f((unsigned short)(d >> 16));
        bool rst = ii[i] > 0.f;
        A = rst ? a : a * A;
        Bv = rst ? bb : fmaf(a, Bv, bb);
        rf |= (int)rst;
    }
    size_t o = ((size_t)b * NCHUNK + chunk) * H_DIM + ch;
    CA[o] = A;
    CB[o] = Bv;
    if (ch == 0) CR[b * NCHUNK + chunk] = (float)rf;
}

__global__ void scan_tops(const float* __restrict__ CA, const float* __restrict__ CB,
                          const float* __restrict__ CR,
                          float* __restrict__ PA, float* __restrict__ PB) {
    int idx = blockIdx.x * blockDim.x + threadIdx.x;   // 0 .. B*H-1
    if (idx >= B_DIM * H_DIM) return;
    int ch = idx & (H_DIM - 1);
    int b = idx >> 10;
    float A = 1.f, Bv = 0.f;
    for (int c = 0; c < NCHUNK; c++) {
        size_t o = ((size_t)b * NCHUNK + c) * H_DIM + ch;
        PA[o] = A;            // exclusive prefix
        PB[o] = Bv;
        float a = CA[o], bb = CB[o];
        bool rst = CR[b * NCHUNK + c] > 0.f;
        float nA = rst ? a : a * A;
        float nB = rst ? bb : fmaf(a, Bv, bb);
        A = nA; Bv = nB;
    }
}

__global__ __launch_bounds__(256) void scan_apply(
    const uint32_t* __restrict__ Sab, const float* __restrict__ is_init,
    const float* __restrict__ PA, const float* __restrict__ PB,
    const float* __restrict__ h0,
    unsigned short* __restrict__ hb, float* __restrict__ hn) {
    int idx = blockIdx.x * 256 + threadIdx.x;
    int ch = idx & (H_DIM - 1);
    int chunk = (idx >> 10) & (NCHUNK - 1);
    int b = idx >> 16;
    int t0 = chunk * CHUNK;
    size_t base = ((size_t)b * T_DIM + t0) * H_DIM + ch;
    const float* ii = is_init + (size_t)b * T_DIM + t0;
    size_t po = ((size_t)b * NCHUNK + chunk) * H_DIM + ch;
    float A = PA[po], Bv = PB[po];
    float h0v = h0[b * H_DIM + ch];
    float h = 0.f;
    for (int i = 0; i < CHUNK; i++) {
        uint32_t d = Sab[base + (size_t)i * H_DIM];
        float a = b2f((unsigned short)(d & 0xffffu));
        float bb = b2f((unsigned short)(d >> 16));
        bool rst = ii[i] > 0.f;
        A = rst ? a : a * A;
        Bv = rst ? bb : fmaf(a, Bv, bb);
        h = fmaf(A, h0v, Bv);
        hb[base + (size_t)i * H_DIM] = f2b(h);
    }
    if (chunk == NCHUNK - 1) hn[b * H_DIM + ch] = h;
}

// ---------------- launcher ----------------

extern "C" void kernel_launch(void* const* d_in, const int* in_sizes, int n_in,
                              void* d_out, int out_size, void* d_ws, size_t ws_size,
                              hipStream_t stream) {
    const float* x       = (const float*)d_in[0];
    const float* W_hg    = (const float*)d_in[1];
    const float* W_out   = (const float*)d_in[2];
    const float* is_init = (const float*)d_in[3];
    const float* h0      = (const float*)d_in[4];
    float* out = (float*)d_out;
    float* hn  = out + (size_t)M_DIM * H_DIM;

    char* ws = (char*)d_ws;
    size_t off = 0;
    auto alloc = [&](size_t bytes) {
        void* p = ws + off;
        off += (bytes + 255) & ~(size_t)255;
        return p;
    };
    unsigned short* xb  = (unsigned short*)alloc((size_t)M_DIM * K_DIM * 2); // reused as hb
    unsigned short* Wp  = (unsigned short*)alloc((size_t)2 * H_DIM * K_DIM * 2);
    unsigned short* Wob = (unsigned short*)alloc((size_t)H_DIM * K_DIM * 2);
    uint32_t* Sab = (uint32_t*)alloc((size_t)M_DIM * H_DIM * 4);
    float* CA = (float*)alloc((size_t)B_DIM * NCHUNK * H_DIM * 4);
    float* CB = (float*)alloc((size_t)B_DIM * NCHUNK * H_DIM * 4);
    float* CR = (float*)alloc((size_t)B_DIM * NCHUNK * 4);
    float* PA = (float*)alloc((size_t)B_DIM * NCHUNK * H_DIM * 4);
    float* PB = (float*)alloc((size_t)B_DIM * NCHUNK * H_DIM * 4);
    unsigned short* hb = xb;   // alias: x_bf16 dead after GEMM1

    // 1) conversions (single launch)
    cvt_all<<<2048, 256, 0, stream>>>(x, W_hg, W_out, xb, Wp, Wob);

    // 2) GEMM1 with fused gating epilogue (N = 2048 interleaved cols)
    gemm1<<<dim3(2048 / 256, M_DIM / 256), 512, 0, stream>>>(
        xb, Wp, Sab, 2048);

    // 3) 3-pass chunked scan over time (packed coefficients)
    scan_chunks<<<(B_DIM * NCHUNK * H_DIM) / 256, 256, 0, stream>>>(
        Sab, is_init, CA, CB, CR);
    scan_tops<<<(B_DIM * H_DIM + 255) / 256, 256, 0, stream>>>(CA, CB, CR, PA, PB);
    scan_apply<<<(B_DIM * NCHUNK * H_DIM) / 256, 256, 0, stream>>>(
        Sab, is_init, PA, PB, h0, hb, hn);

    // 4) GEMM2: out = h @ W_out^T  (single-buffered, 2 blocks/CU)
    gemm2<<<dim3(1024 / 256, M_DIM / 256), 512, 0, stream>>>(
        hb, Wob, out, 1024);
}

// Round 16
// 354.771 us; speedup vs baseline: 2.1167x; 1.9081x over previous
//
#include <hip/hip_runtime.h>
#include <stdint.h>

#define B_DIM 8
#define T_DIM 4096
#define K_DIM 1024
#define H_DIM 1024
#define M_DIM (B_DIM * T_DIM)      // 32768
#define CHUNK 64
#define NCHUNK (T_DIM / CHUNK)     // 64

typedef __attribute__((ext_vector_type(8))) short s16x8;
typedef __attribute__((ext_vector_type(4))) float f32x4;

__device__ __forceinline__ unsigned short f2b(float f) {
    union { float f; uint32_t u; } c; c.f = f;
    uint32_t r = (c.u + 0x7fffu + ((c.u >> 16) & 1u)) >> 16;
    return (unsigned short)r;
}
__device__ __forceinline__ float b2f(unsigned short u) {
    union { uint32_t u; float f; } c; c.u = ((uint32_t)u) << 16;
    return c.f;
}

// async global->LDS, 16B per lane. LDS dest = wave-uniform base + lane*16.
__device__ __forceinline__ void gload_lds16(const unsigned short* g,
                                            unsigned short* l) {
    __builtin_amdgcn_global_load_lds(
        (__attribute__((address_space(1))) void*)g,
        (__attribute__((address_space(3))) void*)l, 16, 0, 0);
}

__device__ __forceinline__ void bar() {
    asm volatile("s_barrier" ::: "memory");
}

// ---------------- merged conversion kernel ----------------

__device__ __forceinline__ ushort4 cvu4(float4 v) {
    ushort4 o;
    o.x = f2b(v.x); o.y = f2b(v.y); o.z = f2b(v.z); o.w = f2b(v.w);
    return o;
}

// x -> xb; W_hg -> interleaved Wp (row 2c=hidden c, 2c+1=gate c); W_out -> Wob
__global__ void cvt_all(const float* __restrict__ x,
                        const float* __restrict__ Whg,
                        const float* __restrict__ Wout,
                        unsigned short* __restrict__ xb,
                        unsigned short* __restrict__ Wp,
                        unsigned short* __restrict__ Wob) {
    const int NX = M_DIM * K_DIM / 4;
    const int NW = 2 * H_DIM * K_DIM / 4;
    const int NO = H_DIM * K_DIM / 4;
    int stride = gridDim.x * blockDim.x;
    for (int i = blockIdx.x * blockDim.x + threadIdx.x; i < NX + NW + NO;
         i += stride) {
        if (i < NX) {
            ((ushort4*)xb)[i] = cvu4(((const float4*)x)[i]);
        } else if (i < NX + NW) {
            int j = i - NX;
            int e = j * 4;
            int n = e >> 10;          // K = 1024
            int k = e & 1023;
            int src = (n & 1) ? (H_DIM + (n >> 1)) : (n >> 1);
            *(ushort4*)&Wp[(size_t)n * K_DIM + k] =
                cvu4(*(const float4*)&Whg[(size_t)src * K_DIM + k]);
        } else {
            int j = i - NX - NW;
            ((ushort4*)Wob)[j] = cvu4(((const float4*)Wout)[j]);
        }
    }
}

// ---------------- 256x256 4-phase bf16 MFMA GEMM (R4 schedule, frozen) ------
// Staging spread 3/3/2 over phases 1-3; validation vmcnt(0) in phase 4.
// dbuf LDS 128KB, XOR slot-swizzle via pre-swizzled global source.
// EPI==0: f32 store. EPI==1: fused minGRU gating epilogue -> packed u32
//         Sab[row][ch] = {lo: bf16(1-g), hi: bf16(g*hidden)}.

template <int EPI>
__global__ __launch_bounds__(512, 2) void gemm256(
    const unsigned short* __restrict__ A,
    const unsigned short* __restrict__ Bm,
    float* __restrict__ C,
    uint32_t* __restrict__ Sab,
    int N) {
    __shared__ unsigned short As[2][256 * 64];
    __shared__ unsigned short Bs[2][256 * 64];
    const int K = K_DIM;
    const int KT = K / 64;

    // T1: bijective XCD swizzle (nwg % 8 == 0 for both GEMMs here)
    const int gx = gridDim.x;
    const int nwg = gx * gridDim.y;
    const int orig = blockIdx.y * gx + blockIdx.x;
    const int cpx = nwg >> 3;
    const int wg = (orig & 7) * cpx + (orig >> 3);
    const int m0 = (wg / gx) * 256;
    const int n0 = (wg % gx) * 256;

    const int t = threadIdx.x;
    const int lane = t & 63;
    const int w = t >> 6;               // 0..7
    const int wm = w >> 2, wn = w & 3;  // 2 x 4 wave grid

    const int lrow = lane >> 3;
    const int lslot = (lane & 7) ^ lrow;

    const int l15 = lane & 15;
    const int rq = lane >> 4;          // 0..3
    const int rx = l15 & 7;

    f32x4 acc[8][4];
#pragma unroll
    for (int m = 0; m < 8; m++)
#pragma unroll
        for (int n = 0; n < 4; n++) acc[m][n] = (f32x4){0.f, 0.f, 0.f, 0.f};

    auto stageA = [&](int kt, int buf, int j) {
        const int seg = j * 8 + w;
        const int row = seg * 8 + lrow;
        gload_lds16(&A[(size_t)(m0 + row) * K + kt * 64 + lslot * 8],
                    &As[buf][seg * 512]);
    };
    auto stageB = [&](int kt, int buf, int j) {
        const int seg = j * 8 + w;
        const int row = seg * 8 + lrow;
        gload_lds16(&Bm[(size_t)(n0 + row) * K + kt * 64 + lslot * 8],
                    &Bs[buf][seg * 512]);
    };

    s16x8 af[4], bf[4];

#define LDA(buf, mi, ks) \
    (*(const s16x8*)&As[buf][(wm * 128 + (mi) * 16 + l15) * 64 + (((rq + (ks) * 4) ^ rx) * 8)])
#define LDB(buf, ni, ks) \
    (*(const s16x8*)&Bs[buf][(wn * 64 + (ni) * 16 + l15) * 64 + (((rq + (ks) * 4) ^ rx) * 8)])

#define MFMA16(MB)                                                          \
    __builtin_amdgcn_s_setprio(1);                                          \
    _Pragma("unroll") for (int m = 0; m < 4; m++)                           \
        _Pragma("unroll") for (int n = 0; n < 4; n++)                       \
            acc[MB + m][n] = __builtin_amdgcn_mfma_f32_16x16x32_bf16(       \
                af[m], bf[n], acc[MB + m][n], 0, 0, 0);                     \
    __builtin_amdgcn_s_setprio(0);

    // prologue: stage tile 0 fully, validate
    {
#pragma unroll
        for (int j = 0; j < 4; j++) stageA(0, 0, j);
#pragma unroll
        for (int j = 0; j < 4; j++) stageB(0, 0, j);
        asm volatile("s_waitcnt vmcnt(0)" ::: "memory");
        bar();
    }

    for (int kt = 0; kt < KT; ++kt) {
        const int buf = kt & 1;
        const int nb = buf ^ 1;
        const bool nx = (kt + 1 < KT);
        // ---- phase 1
#pragma unroll
        for (int m = 0; m < 4; m++) af[m] = LDA(buf, m, 0);
#pragma unroll
        for (int n = 0; n < 4; n++) bf[n] = LDB(buf, n, 0);
        if (nx) { stageA(kt + 1, nb, 0); stageA(kt + 1, nb, 1); stageB(kt + 1, nb, 0); }
        bar();
        MFMA16(0);
        bar();
        // ---- phase 2
#pragma unroll
        for (int m = 0; m < 4; m++) af[m] = LDA(buf, m + 4, 0);
        if (nx) { stageA(kt + 1, nb, 2); stageA(kt + 1, nb, 3); stageB(kt + 1, nb, 1); }
        bar();
        MFMA16(4);
        bar();
        // ---- phase 3
#pragma unroll
        for (int m = 0; m < 4; m++) af[m] = LDA(buf, m, 1);
#pragma unroll
        for (int n = 0; n < 4; n++) bf[n] = LDB(buf, n, 1);
        if (nx) { stageB(kt + 1, nb, 2); stageB(kt + 1, nb, 3); }
        bar();
        MFMA16(0);
        bar();
        // ---- phase 4: pipelined validation of tile kt+1
#pragma unroll
        for (int m = 0; m < 4; m++) af[m] = LDA(buf, m + 4, 1);
        asm volatile("s_waitcnt vmcnt(0)" ::: "memory");
        bar();
        MFMA16(4);
        bar();
    }

    // ---- epilogue
    const int lr4 = rq * 4;
#pragma unroll
    for (int m = 0; m < 8; m++) {
#pragma unroll
        for (int n = 0; n < 4; n++) {
#pragma unroll
            for (int r = 0; r < 4; r++) {
                const int row = m0 + wm * 128 + m * 16 + lr4 + r;
                const int col = n0 + wn * 64 + n * 16 + l15;
                float v = acc[m][n][r];
                if (EPI == 0) {
                    C[(size_t)row * N + col] = v;
                } else {
                    float o = __shfl_xor(v, 1);   // all lanes execute
                    if ((lane & 1) == 0) {
                        // even lane: v = hidden, o = gate logit -> pack both
                        float g = 1.f / (1.f + __expf(-o));
                        uint32_t pk = (uint32_t)f2b(1.f - g) |
                                      ((uint32_t)f2b(g * v) << 16);
                        Sab[(size_t)row * H_DIM + (col >> 1)] = pk;
                    }
                }
            }
        }
    }
#undef LDA
#undef LDB
#undef MFMA16
}

// ---------------- chunked scan (3-pass, packed coefficients) ----------------
// Element combine (matches reference): carry (A,Bv); element (a,b,r):
//   r>0 : (A,Bv) = (a, b)      else : (A,Bv) = (a*A, a*Bv + b)

__global__ __launch_bounds__(256) void scan_chunks(
    const uint32_t* __restrict__ Sab, const float* __restrict__ is_init,
    float* __restrict__ CA, float* __restrict__ CB, float* __restrict__ CR) {
    int idx = blockIdx.x * 256 + threadIdx.x;      // b*65536 + chunk*1024 + ch
    int ch = idx & (H_DIM - 1);
    int chunk = (idx >> 10) & (NCHUNK - 1);
    int b = idx >> 16;
    int t0 = chunk * CHUNK;
    size_t base = ((size_t)b * T_DIM + t0) * H_DIM + ch;
    const float* ii = is_init + (size_t)b * T_DIM + t0;
    float A = 1.f, Bv = 0.f;
    int rf = 0;
    for (int i = 0; i < CHUNK; i++) {
        uint32_t d = Sab[base + (size_t)i * H_DIM];
        float a = b2f((unsigned short)(d & 0xffffu));
        float bb = b2f((unsigned short)(d >> 16));
        bool rst = ii[i] > 0.f;
        A = rst ? a : a * A;
        Bv = rst ? bb : fmaf(a, Bv, bb);
        rf |= (int)rst;
    }
    size_t o = ((size_t)b * NCHUNK + chunk) * H_DIM + ch;
    CA[o] = A;
    CB[o] = Bv;
    if (ch == 0) CR[b * NCHUNK + chunk] = (float)rf;
}

__global__ void scan_tops(const float* __restrict__ CA, const float* __restrict__ CB,
                          const float* __restrict__ CR,
                          float* __restrict__ PA, float* __restrict__ PB) {
    int idx = blockIdx.x * blockDim.x + threadIdx.x;   // 0 .. B*H-1
    if (idx >= B_DIM * H_DIM) return;
    int ch = idx & (H_DIM - 1);
    int b = idx >> 10;
    float A = 1.f, Bv = 0.f;
    for (int c = 0; c < NCHUNK; c++) {
        size_t o = ((size_t)b * NCHUNK + c) * H_DIM + ch;
        PA[o] = A;            // exclusive prefix
        PB[o] = Bv;
        float a = CA[o], bb = CB[o];
        bool rst = CR[b * NCHUNK + c] > 0.f;
        float nA = rst ? a : a * A;
        float nB = rst ? bb : fmaf(a, Bv, bb);
        A = nA; Bv = nB;
    }
}

__global__ __launch_bounds__(256) void scan_apply(
    const uint32_t* __restrict__ Sab, const float* __restrict__ is_init,
    const float* __restrict__ PA, const float* __restrict__ PB,
    const float* __restrict__ h0,
    unsigned short* __restrict__ hb, float* __restrict__ hn) {
    int idx = blockIdx.x * 256 + threadIdx.x;
    int ch = idx & (H_DIM - 1);
    int chunk = (idx >> 10) & (NCHUNK - 1);
    int b = idx >> 16;
    int t0 = chunk * CHUNK;
    size_t base = ((size_t)b * T_DIM + t0) * H_DIM + ch;
    const float* ii = is_init + (size_t)b * T_DIM + t0;
    size_t po = ((size_t)b * NCHUNK + chunk) * H_DIM + ch;
    float A = PA[po], Bv = PB[po];
    float h0v = h0[b * H_DIM + ch];
    float h = 0.f;
    for (int i = 0; i < CHUNK; i++) {
        uint32_t d = Sab[base + (size_t)i * H_DIM];
        float a = b2f((unsigned short)(d & 0xffffu));
        float bb = b2f((unsigned short)(d >> 16));
        bool rst = ii[i] > 0.f;
        A = rst ? a : a * A;
        Bv = rst ? bb : fmaf(a, Bv, bb);
        h = fmaf(A, h0v, Bv);
        hb[base + (size_t)i * H_DIM] = f2b(h);
    }
    if (chunk == NCHUNK - 1) hn[b * H_DIM + ch] = h;
}

// ---------------- launcher ----------------

extern "C" void kernel_launch(void* const* d_in, const int* in_sizes, int n_in,
                              void* d_out, int out_size, void* d_ws, size_t ws_size,
                              hipStream_t stream) {
    const float* x       = (const float*)d_in[0];
    const float* W_hg    = (const float*)d_in[1];
    const float* W_out   = (const float*)d_in[2];
    const float* is_init = (const float*)d_in[3];
    const float* h0      = (const float*)d_in[4];
    float* out = (float*)d_out;
    float* hn  = out + (size_t)M_DIM * H_DIM;

    char* ws = (char*)d_ws;
    size_t off = 0;
    auto alloc = [&](size_t bytes) {
        void* p = ws + off;
        off += (bytes + 255) & ~(size_t)255;
        return p;
    };
    unsigned short* xb  = (unsigned short*)alloc((size_t)M_DIM * K_DIM * 2); // reused as hb
    unsigned short* Wp  = (unsigned short*)alloc((size_t)2 * H_DIM * K_DIM * 2);
    unsigned short* Wob = (unsigned short*)alloc((size_t)H_DIM * K_DIM * 2);
    uint32_t* Sab = (uint32_t*)alloc((size_t)M_DIM * H_DIM * 4);
    float* CA = (float*)alloc((size_t)B_DIM * NCHUNK * H_DIM * 4);
    float* CB = (float*)alloc((size_t)B_DIM * NCHUNK * H_DIM * 4);
    float* CR = (float*)alloc((size_t)B_DIM * NCHUNK * 4);
    float* PA = (float*)alloc((size_t)B_DIM * NCHUNK * H_DIM * 4);
    float* PB = (float*)alloc((size_t)B_DIM * NCHUNK * H_DIM * 4);
    unsigned short* hb = xb;   // alias: x_bf16 dead after GEMM1

    // 1) conversions (single launch)
    cvt_all<<<2048, 256, 0, stream>>>(x, W_hg, W_out, xb, Wp, Wob);

    // 2) GEMM1 with fused gating epilogue (N = 2048 interleaved cols)
    gemm256<1><<<dim3(2048 / 256, M_DIM / 256), 512, 0, stream>>>(
        xb, Wp, nullptr, Sab, 2048);

    // 3) 3-pass chunked scan over time (packed coefficients)
    scan_chunks<<<(B_DIM * NCHUNK * H_DIM) / 256, 256, 0, stream>>>(
        Sab, is_init, CA, CB, CR);
    scan_tops<<<(B_DIM * H_DIM + 255) / 256, 256, 0, stream>>>(CA, CB, CR, PA, PB);
    scan_apply<<<(B_DIM * NCHUNK * H_DIM) / 256, 256, 0, stream>>>(
        Sab, is_init, PA, PB, h0, hb, hn);

    // 4) GEMM2: out = h @ W_out^T
    gemm256<0><<<dim3(1024 / 256, M_DIM / 256), 512, 0, stream>>>(
        hb, Wob, out, nullptr, 1024);
}